// Round 3
// baseline (1656.617 us; speedup 1.0000x reference)
//
#include <hip/hip_runtime.h>

// VanillaLSTM fused, round 2 resubmit (round-2 bench died in infra, no logs).
// Force v_pk_fma_f32 (packed fp32, 2 seqs/lane) with SGPR-broadcast weights
// via inline asm + op_sel. Weights stream through the scalar pipe (s_load,
// K$-resident, ~10.5 KB), MACs are 1 instr / 4 FLOPs per lane. Steps
// t > T_pred are skipped (reference zeroes them).

typedef float v2f __attribute__((ext_vector_type(2)));

#define TSTEPS 64
#define H 20
#define M 10

static __device__ __forceinline__ v2f sp(float s){ v2f r; r.x = s; r.y = s; return r; }
static __device__ __forceinline__ v2f mk(float a, float b){ v2f r; r.x = a; r.y = b; return r; }

// acc.xy += w.x * h.xy   (broadcast LOW word of SGPR pair to both halves)
static __device__ __forceinline__ void pk_fma_lo(v2f& acc, v2f w, v2f h){
    asm("v_pk_fma_f32 %0, %1, %2, %0 op_sel:[0,0,0] op_sel_hi:[0,1,1]"
        : "+v"(acc) : "s"(w), "v"(h));
}
// acc.xy += w.y * h.xy   (broadcast HIGH word)
static __device__ __forceinline__ void pk_fma_hi(v2f& acc, v2f w, v2f h){
    asm("v_pk_fma_f32 %0, %1, %2, %0 op_sel:[1,0,0] op_sel_hi:[1,1,1]"
        : "+v"(acc) : "s"(w), "v"(h));
}

static __device__ __forceinline__ float sigm1(float x){
    return __builtin_amdgcn_rcpf(1.0f + __expf(-x));
}
static __device__ __forceinline__ v2f sigm(v2f x){ return mk(sigm1(x.x), sigm1(x.y)); }

static __device__ __forceinline__ float tanh1(float x){
    return 1.0f - 2.0f * __builtin_amdgcn_rcpf(__expf(2.0f * x) + 1.0f);
}
static __device__ __forceinline__ v2f tanhv(v2f x){ return mk(tanh1(x.x), tanh1(x.y)); }

__global__ __launch_bounds__(256)
void lstm_fused(const float* __restrict__ X,
                const int*   __restrict__ pm,
                const float* __restrict__ h0,
                const float* __restrict__ c0,
                const float* __restrict__ Yv,
                const int*   __restrict__ tobs_p,
                const int*   __restrict__ tpred_p,
                const float* __restrict__ W_in,  const float* __restrict__ b_in,
                const float* __restrict__ W_ih,  const float* __restrict__ W_hh,
                const float* __restrict__ b_ih,  const float* __restrict__ b_hh,
                const float* __restrict__ W_out, const float* __restrict__ b_out,
                float* __restrict__ outp, int N)
{
    const int tid  = blockIdx.x * blockDim.x + threadIdx.x;
    const int half = N >> 1;
    if (tid >= half) return;
    const int n0 = tid;            // lane's sequence A
    const int n1 = tid + half;     // lane's sequence B
    const int T_obs  = *tobs_p;
    const int T_pred = *tpred_p;
    const int tmax   = (T_pred < TSTEPS - 1) ? T_pred : (TSTEPS - 1);

    // recurrent state in registers (packed: .x = seq A, .y = seq B)
    v2f h[H], c[H];
#pragma unroll
    for (int j = 0; j < H; ++j){
        h[j] = mk(h0[(size_t)n0*H + j], h0[(size_t)n1*H + j]);
        c[j] = mk(c0[(size_t)n0*H + j], c0[(size_t)n1*H + j]);
    }

    v2f q0 = sp(1.f), q1 = sp(1.f), q2 = sp(1.f);   // m_prev3 rolling queue
    v2f po0 = sp(0.f), po1 = sp(0.f);               // prev output

    int pm0 = pm[n0];
    int pm1 = pm[n1];
    v2f x0, x1;
    {
        v2f xa = *(const v2f*)(X + ((size_t)0*N + n0)*4 + 2);
        v2f xb = *(const v2f*)(X + ((size_t)0*N + n1)*4 + 2);
        x0 = mk(xa.x, xb.x);
        x1 = mk(xa.y, xb.y);
    }

#pragma unroll 1
    for (int t = 0; t <= tmax; ++t){
        const v2f mt  = mk((float)pm0, (float)pm1);
        const v2f mp3 = q0; q0 = q1; q1 = q2; q2 = mt;

        v2f in0, in1;
        if (t <= T_obs){ in0 = x0; in1 = x1; }       // uniform branch
        else           { in0 = po0; in1 = po1; }

        // prefetch next step's mask / X
        if (t < tmax){
            pm0 = pm[(size_t)(t+1)*N + n0];
            pm1 = pm[(size_t)(t+1)*N + n1];
            if (t + 1 <= T_obs){
                v2f xa = *(const v2f*)(X + ((size_t)(t+1)*N + n0)*4 + 2);
                v2f xb = *(const v2f*)(X + ((size_t)(t+1)*N + n1)*4 + 2);
                x0 = mk(xa.x, xb.x);
                x1 = mk(xa.y, xb.y);
            }
        }

        // early Y fetch for overwrite lanes
        const bool ow_u = (t > 3) && (t > T_obs);
        bool ow_a = false, ow_b = false;
        v2f y0 = sp(0.f), y1 = sp(0.f);
        if (ow_u){
            ow_a = (mt.x != 0.f) && (mp3.x == 0.f);
            ow_b = (mt.y != 0.f) && (mp3.y == 0.f);
            if (ow_a){ v2f ya = *(const v2f*)(Yv + ((size_t)t*N + n0)*2); y0.x = ya.x; y1.x = ya.y; }
            if (ow_b){ v2f yb = *(const v2f*)(Yv + ((size_t)t*N + n1)*2); y0.y = yb.x; y1.y = yb.y; }
        }

        // ---- r = relu(inp @ W_in.T + b_in) ----
        v2f r[M];
#pragma unroll
        for (int mm = 0; mm < M; ++mm){
            v2f a = sp(b_in[mm]);
            v2f w = *(const v2f*)(W_in + mm*2);      // (w0,w1) pair, 8B aligned
            pk_fma_lo(a, w, in0);
            pk_fma_hi(a, w, in1);
            r[mm] = mk(fmaxf(a.x, 0.f), fmaxf(a.y, 0.f));
        }

        // ---- gates + cell update (fully unrolled; all indices compile-time) ----
        v2f hn[H];
#pragma unroll
        for (int jj = 0; jj < H; ++jj){
            v2f ai = sp(b_ih[jj]       + b_hh[jj]);
            v2f af = sp(b_ih[H+jj]     + b_hh[H+jj]);
            v2f ag = sp(b_ih[2*H+jj]   + b_hh[2*H+jj]);
            v2f ao = sp(b_ih[3*H+jj]   + b_hh[3*H+jj]);

            const float* wi0 = W_ih + (jj      )*M;
            const float* wi1 = W_ih + (H   + jj)*M;
            const float* wi2 = W_ih + (2*H + jj)*M;
            const float* wi3 = W_ih + (3*H + jj)*M;
#pragma unroll
            for (int k = 0; k < M; k += 2){
                v2f w0 = *(const v2f*)(wi0 + k);
                v2f w1 = *(const v2f*)(wi1 + k);
                v2f w2 = *(const v2f*)(wi2 + k);
                v2f w3 = *(const v2f*)(wi3 + k);
                const v2f ra = r[k], rb = r[k+1];
                pk_fma_lo(ai, w0, ra); pk_fma_hi(ai, w0, rb);
                pk_fma_lo(af, w1, ra); pk_fma_hi(af, w1, rb);
                pk_fma_lo(ag, w2, ra); pk_fma_hi(ag, w2, rb);
                pk_fma_lo(ao, w3, ra); pk_fma_hi(ao, w3, rb);
            }

            const float* wh0 = W_hh + (jj      )*H;
            const float* wh1 = W_hh + (H   + jj)*H;
            const float* wh2 = W_hh + (2*H + jj)*H;
            const float* wh3 = W_hh + (3*H + jj)*H;
#pragma unroll
            for (int k = 0; k < H; k += 2){
                v2f w0 = *(const v2f*)(wh0 + k);
                v2f w1 = *(const v2f*)(wh1 + k);
                v2f w2 = *(const v2f*)(wh2 + k);
                v2f w3 = *(const v2f*)(wh3 + k);
                const v2f ha = h[k], hb = h[k+1];
                pk_fma_lo(ai, w0, ha); pk_fma_hi(ai, w0, hb);
                pk_fma_lo(af, w1, ha); pk_fma_hi(af, w1, hb);
                pk_fma_lo(ag, w2, ha); pk_fma_hi(ag, w2, hb);
                pk_fma_lo(ao, w3, ha); pk_fma_hi(ao, w3, hb);
            }

            const v2f cn = sigm(af) * c[jj] + sigm(ai) * tanhv(ag);
            const v2f hv = sigm(ao) * tanhv(cn);
            c[jj]  = cn;          // loop only covers active steps
            hn[jj] = hv;
        }

        // ---- out = (h_new @ W_out.T + b_out) * m ----
        v2f o0 = sp(b_out[0]), o1 = sp(b_out[1]);
#pragma unroll
        for (int k = 0; k < H; k += 2){
            v2f w0 = *(const v2f*)(W_out + k);       // row 0 pair
            v2f w1 = *(const v2f*)(W_out + H + k);   // row 1 pair
            const v2f ha = hn[k], hb = hn[k+1];
            pk_fma_lo(o0, w0, ha); pk_fma_hi(o0, w0, hb);
            pk_fma_lo(o1, w1, ha); pk_fma_hi(o1, w1, hb);
        }
        o0 *= mt; o1 *= mt;

        if (ow_a){ o0.x = y0.x; o1.x = y1.x; }
        if (ow_b){ o0.y = y0.y; o1.y = y1.y; }

#pragma unroll
        for (int j = 0; j < H; ++j) h[j] = hn[j];

        *(v2f*)(outp + ((size_t)t*N + n0)*2) = mk(o0.x, o1.x);
        *(v2f*)(outp + ((size_t)t*N + n1)*2) = mk(o0.y, o1.y);
        po0 = o0; po1 = o1;
    }

    // tail: reference zeroes outputs for t > T_pred (h/c frozen, irrelevant)
#pragma unroll 1
    for (int t = tmax + 1; t < TSTEPS; ++t){
        *(v2f*)(outp + ((size_t)t*N + n0)*2) = sp(0.f);
        *(v2f*)(outp + ((size_t)t*N + n1)*2) = sp(0.f);
    }
}

extern "C" void kernel_launch(void* const* d_in, const int* in_sizes, int n_in,
                              void* d_out, int out_size, void* d_ws, size_t ws_size,
                              hipStream_t stream)
{
    const float* X     = (const float*)d_in[0];
    const int*   pmk   = (const int*)  d_in[1];
    const float* h0    = (const float*)d_in[2];
    const float* c0    = (const float*)d_in[3];
    const float* Yv    = (const float*)d_in[4];
    const int*   tobs  = (const int*)  d_in[5];
    const int*   tpred = (const int*)  d_in[6];
    const float* W_in  = (const float*)d_in[7];
    const float* b_in  = (const float*)d_in[8];
    const float* W_ih  = (const float*)d_in[9];
    const float* W_hh  = (const float*)d_in[10];
    const float* b_ih  = (const float*)d_in[11];
    const float* b_hh  = (const float*)d_in[12];
    const float* W_out = (const float*)d_in[13];
    const float* b_out = (const float*)d_in[14];
    float* outp = (float*)d_out;

    const int N = in_sizes[1] / TSTEPS;   // part_masks is (T,1,N)
    const int threads = N / 2;            // 2 sequences per thread (packed fp32)
    const int block = 256;
    const int grid = (threads + block - 1) / block;

    hipLaunchKernelGGL(lstm_fused, dim3(grid), dim3(block), 0, stream,
                       X, pmk, h0, c0, Yv, tobs, tpred,
                       W_in, b_in, W_ih, W_hh, b_ih, b_hh, W_out, b_out,
                       outp, N);
}